// Round 11
// baseline (480.697 us; speedup 1.0000x reference)
//
#include <hip/hip_runtime.h>
#include <math.h>

#define BB 32
#define NN 1024
#define BN (BB*NN)
#define KS 24
#define KCH 128

__device__ __forceinline__ float sigmoidf_(float v) { return 1.0f / (1.0f + expf(-v)); }
__device__ __forceinline__ unsigned f2bf(float f) {           // round-to-nearest-even bf16 bits
  unsigned u = __float_as_uint(f);
  return (u + 0x7fffu + ((u >> 16) & 1u)) >> 16;
}
__device__ __forceinline__ float bflo(unsigned u) { return __uint_as_float(u << 16); }
__device__ __forceinline__ float bfhi(unsigned u) { return __uint_as_float(u & 0xffff0000u); }

// ---------------- zero c ----------------
__global__ void k_zero(float* __restrict__ c) {
  int i = blockIdx.x * 256 + threadIdx.x;
  c[i] = 0.0f;
}

// ---------------- embedding: emb[row][256] fp32 + embh[row][128] packed bf16x2 ----------------
__global__ void k_emb(const int* __restrict__ xint, const float* __restrict__ xyz,
                      const float* __restrict__ am, const float* __restrict__ el,
                      const float* __restrict__ po, const float* __restrict__ xw,
                      const float* __restrict__ xb, float* __restrict__ emb,
                      unsigned* __restrict__ embh) {
  __shared__ float sv[256];
  int row = blockIdx.x;
  int d = threadIdx.x;
  int i0 = xint[row*3+0], i1 = xint[row*3+1], i2 = xint[row*3+2];
  float v;
  if (d < 28)        v = am[i0*28 + d];
  else if (d < 56)   v = el[i1*28 + (d-28)];
  else if (d < 84)   v = po[i2*28 + (d-56)];
  else {
    int o = d - 84;
    float x0 = xyz[row*3+0], x1 = xyz[row*3+1], x2 = xyz[row*3+2];
    v = fmaxf(xw[o*3+0]*x0 + xw[o*3+1]*x1 + xw[o*3+2]*x2 + xb[o], 0.0f);
  }
  emb[(size_t)row*256 + d] = v;
  sv[d] = v;
  __syncthreads();
  if (d < 128) {
    unsigned u = (f2bf(sv[d*2+1]) << 16) | f2bf(sv[d*2]);
    embh[(size_t)row*128 + d] = u;
  }
}

// ---------------- transpose+quantize weights: wt2[k2][j] = pack(bf16 w[2k2][j], bf16 w[2k2+1][j]) ----------------
__global__ __launch_bounds__(256) void k_wt(const float* __restrict__ w_ih,
        const float* __restrict__ w_hh, unsigned* __restrict__ wt2) {
  __shared__ float t[32][33];
  int jt = blockIdx.x * 32, kt = blockIdx.y * 32;
  int tx = threadIdx.x & 31, ty = threadIdx.x >> 5;   // ty 0..7
#pragma unroll
  for (int i = 0; i < 4; i++) {
    int j = jt + ty + i*8;
    int k = kt + tx;
    float v = (k < 2048) ? w_ih[(size_t)j*2048 + k] : w_hh[(size_t)j*1024 + (k - 2048)];
    t[ty + i*8][tx] = v;                              // t[j_local][k_local]
  }
  __syncthreads();
#pragma unroll
  for (int i = 0; i < 2; i++) {
    int kl2 = ty + i*8;                               // 0..15
    float lo = t[tx][kl2*2], hi = t[tx][kl2*2+1];
    unsigned u = (f2bf(hi) << 16) | f2bf(lo);
    wt2[(size_t)((kt >> 1) + kl2)*4096 + jt + tx] = u;
  }
}

// ---------------- Wc partials: wcp[och][k][d] ----------------
__global__ void k_wc1(const float* __restrict__ up_w, const float* __restrict__ att1w,
                      float* __restrict__ wcp) {
  int k = blockIdx.x;       // 128
  int och = blockIdx.y;     // 8
  int d = threadIdx.x;      // 256
  __shared__ float s[128];
  int o0 = och*128;
  if (d < 128) s[d] = att1w[(size_t)k*2048 + 1024 + o0 + d];
  __syncthreads();
  float acc = 0.0f;
#pragma unroll 8
  for (int oi = 0; oi < 128; oi++) acc += up_w[(size_t)(o0+oi)*256 + d] * s[oi];
  wcp[((size_t)och*128 + k)*256 + d] = acc;
}

__global__ void k_wc2(const float* __restrict__ wcp, float* __restrict__ wc) {
  int k = blockIdx.x, d = threadIdx.x;
  float s = 0.0f;
#pragma unroll
  for (int p = 0; p < 8; p++) s += wcp[((size_t)p*128 + k)*256 + d];
  wc[k*256 + d] = s;
}

// ---------------- bc[k] = sum_o up_b[o] * att1_w[k][1024+o] ----------------
__global__ void k_bc(const float* __restrict__ up_b, const float* __restrict__ att1w,
                     float* __restrict__ bc) {
  int k = blockIdx.x;   // 128 blocks x 64 threads
  int t = threadIdx.x;
  float acc = 0.0f;
#pragma unroll
  for (int i = 0; i < 4; i++) {
    int o = i*256 + t*4;
    float4 a4 = *(const float4*)(att1w + (size_t)k*2048 + 1024 + o);
    float4 b4 = *(const float4*)(up_b + o);
    acc += a4.x*b4.x + a4.y*b4.y + a4.z*b4.z + a4.w*b4.w;
  }
#pragma unroll
  for (int m = 32; m >= 1; m >>= 1) acc += __shfl_xor(acc, m, 64);
  if (t == 0) bc[k] = acc;
}

// ---------------- fp32 GEMM 32x128 tile, BK=32: xah = bf16pack(emb @ wc^T + bc) ----------------
__global__ __launch_bounds__(256) void k_gemm32(const float* __restrict__ A,
        const float* __restrict__ W, const float* __restrict__ bias,
        unsigned* __restrict__ Ch) {
  __shared__ float As[32][33];
  __shared__ float Bs[32][133];     // 4*133 = 532 = 20 mod 32 -> conflict-free kq spread
  const int m0 = blockIdx.x * 32;
  const int tid = threadIdx.x;
  const int tx = tid & 15, ty = tid >> 4;
  float acc[2][8];
#pragma unroll
  for (int i = 0; i < 2; i++)
#pragma unroll
    for (int j = 0; j < 8; j++) acc[i][j] = 0.0f;

  for (int kt = 0; kt < 256; kt += 32) {
    {
      int r = tid >> 3;               // 0..31
      int kq = (tid & 7) * 4;         // 0..28
      float4 a4 = *(const float4*)(A + (size_t)(m0 + r)*256 + kt + kq);
      As[kq+0][r] = a4.x; As[kq+1][r] = a4.y; As[kq+2][r] = a4.z; As[kq+3][r] = a4.w;
    }
#pragma unroll
    for (int i = 0; i < 4; i++) {
      int s = tid + i*256;            // 0..1023
      int n = s >> 3;                 // 0..127
      int kq = (s & 7) * 4;
      float4 b4 = *(const float4*)(W + (size_t)n*256 + kt + kq);
      Bs[kq+0][n] = b4.x; Bs[kq+1][n] = b4.y; Bs[kq+2][n] = b4.z; Bs[kq+3][n] = b4.w;
    }
    __syncthreads();
#pragma unroll
    for (int kk = 0; kk < 32; kk++) {
      float a0 = As[kk][ty*2], a1 = As[kk][ty*2+1];
      float4 b0 = *(const float4*)&Bs[kk][tx*4];
      float4 b1 = *(const float4*)&Bs[kk][64 + tx*4];
      float bv[8] = {b0.x,b0.y,b0.z,b0.w,b1.x,b1.y,b1.z,b1.w};
#pragma unroll
      for (int j = 0; j < 8; j++) { acc[0][j] += a0*bv[j]; acc[1][j] += a1*bv[j]; }
    }
    __syncthreads();
  }
#pragma unroll
  for (int i = 0; i < 2; i++) {
    int row = m0 + ty*2 + i;
#pragma unroll
    for (int ch = 0; ch < 2; ch++) {
      int col = ch*64 + tx*4;
      float c0 = acc[i][ch*4+0] + bias[col+0];
      float c1 = acc[i][ch*4+1] + bias[col+1];
      float c2 = acc[i][ch*4+2] + bias[col+2];
      float c3 = acc[i][ch*4+3] + bias[col+3];
      uint2 o;
      o.x = (f2bf(c1) << 16) | f2bf(c0);
      o.y = (f2bf(c3) << 16) | f2bf(c2);
      *(uint2*)(Ch + (size_t)row*64 + col/2) = o;
    }
  }
}

// ---------------- gates partials over bf16-packed transposed weights ----------------
// grid (32 jb, nks); block 256; each block: 128 j x 32 b for one 128-k slice
__global__ __launch_bounds__(256) void k_gates(const float* __restrict__ P, const float* __restrict__ h,
        const unsigned* __restrict__ wt2, float* __restrict__ gp) {
  __shared__ float Xs[32][KCH];     // 16 KB
  int jb = blockIdx.x;              // 0..31
  int ks = blockIdx.y;              // 0..nks-1
  int tid = threadIdx.x;
  int kglob = ks * KCH;
  const float* src; int soff;
  if (ks < 8)       { src = P; soff = kglob; }
  else if (ks < 16) { src = h; soff = kglob - 1024; }
  else              { src = h; soff = kglob - 2048; }
#pragma unroll
  for (int i = 0; i < 4; i++) {
    int s = tid + i*256;            // float4 idx 0..1023
    int b = s >> 5, k4 = s & 31;
    *(float4*)&Xs[b][k4*4] = *(const float4*)(src + b*1024 + soff + k4*4);
  }
  __syncthreads();

  int jg = tid & 31, bg = tid >> 5;        // 32 j-groups x 8 b-groups
  int j0 = jb*128 + jg*4;
  int b0 = bg*4;
  const unsigned* wr = wt2 + (size_t)(ks*64)*4096 + j0;
  float acc[4][4];
#pragma unroll
  for (int i = 0; i < 4; i++)
#pragma unroll
    for (int j = 0; j < 4; j++) acc[i][j] = 0.0f;

  for (int k2 = 0; k2 < KCH/2; k2++) {
    uint4 u4 = *(const uint4*)(wr + (size_t)k2*4096);
    float wlo[4], whi[4];
    wlo[0] = bflo(u4.x); whi[0] = bfhi(u4.x);
    wlo[1] = bflo(u4.y); whi[1] = bfhi(u4.y);
    wlo[2] = bflo(u4.z); whi[2] = bfhi(u4.z);
    wlo[3] = bflo(u4.w); whi[3] = bfhi(u4.w);
    int k = k2*2;
#pragma unroll
    for (int bi = 0; bi < 4; bi++) {
      float x0 = Xs[b0+bi][k], x1 = Xs[b0+bi][k+1];
#pragma unroll
      for (int ji = 0; ji < 4; ji++) acc[ji][bi] += wlo[ji]*x0 + whi[ji]*x1;
    }
  }
#pragma unroll
  for (int bi = 0; bi < 4; bi++) {
    float4 v = make_float4(acc[0][bi], acc[1][bi], acc[2][bi], acc[3][bi]);
    *(float4*)(gp + ((size_t)ks*32 + b0 + bi)*4096 + j0) = v;
  }
}

// ---------------- reduce gates (nks partials) + LSTM cell + ra partials per dch ----------------
__global__ __launch_bounds__(256) void k_lstm_rap(const float* __restrict__ gp,
        const float* __restrict__ b_ih, const float* __restrict__ b_hh,
        float* __restrict__ c, float* __restrict__ h,
        const float* __restrict__ att1w, float* __restrict__ rap,
        int need_ra, int nks) {
  int wb = blockIdx.x;             // 128 = b(32) x dch(4)
  int b = wb >> 2, dch = wb & 3;
  int tid = threadIdx.x;
  int d = dch*256 + tid;
  __shared__ float hs[256];
  float gi = b_ih[d]        + b_hh[d];
  float gf = b_ih[1024 + d] + b_hh[1024 + d];
  float gg = b_ih[2048 + d] + b_hh[2048 + d];
  float go = b_ih[3072 + d] + b_hh[3072 + d];
#pragma unroll 4
  for (int ks = 0; ks < nks; ks++) {
    const float* base = gp + ((size_t)ks*32 + b)*4096;
    gi += base[d]; gf += base[1024 + d]; gg += base[2048 + d]; go += base[3072 + d];
  }
  size_t ci = (size_t)b*1024 + d;
  float cn = sigmoidf_(gf)*c[ci] + sigmoidf_(gi)*tanhf(gg);
  c[ci] = cn;
  float hn = sigmoidf_(go)*tanhf(cn);
  h[ci] = hn;
  hs[tid] = hn;
  __syncthreads();
  if (need_ra) {
    int k = tid >> 1, half = tid & 1;
    const float* wr = att1w + (size_t)k*2048 + dch*256 + half*128;
    float acc = 0.0f;
#pragma unroll 8
    for (int i = 0; i < 32; i++) {
      float4 w4 = *(const float4*)(wr + i*4);
      int dl = half*128 + i*4;
      acc += w4.x*hs[dl] + w4.y*hs[dl+1] + w4.z*hs[dl+2] + w4.w*hs[dl+3];
    }
    acc += __shfl_xor(acc, 1, 64);
    if (half == 0) rap[((size_t)dch*32 + b)*128 + k] = acc;
  }
}

// ---------------- fused logits + softmax + pooled bf16-emb partials ----------------
// 128 blocks = b(32) x nch(4). xah==nullptr -> uniform weights (initial mean).
__global__ __launch_bounds__(256) void k_pool_att(const unsigned* __restrict__ xah,
        const float* __restrict__ rap, const float* __restrict__ att1b,
        const float* __restrict__ att2w, const float* __restrict__ att2b,
        const unsigned* __restrict__ embh, float* __restrict__ pp) {
  int wb = blockIdx.x;
  int b = wb >> 2, nch = wb & 3;
  int tid = threadIdx.x;
  __shared__ float rb[128], w2[128];
  __shared__ float lgs[1024];
  __shared__ float red[256];
  __shared__ float ws[256];
  if (xah) {
    if (tid < 128) {
      float r = rap[(size_t)(0  + b)*128 + tid] + rap[(size_t)(32 + b)*128 + tid]
              + rap[(size_t)(64 + b)*128 + tid] + rap[(size_t)(96 + b)*128 + tid];
      rb[tid] = r + att1b[tid];
      w2[tid] = att2w[tid];
    }
    __syncthreads();
    float a2b = att2b[0];
#pragma unroll
    for (int i = 0; i < 4; i++) {
      int n = tid + i*256;
      const uint4* xr = (const uint4*)(xah + ((size_t)b*1024 + n)*64);
      float acc = a2b;
#pragma unroll 4
      for (int q = 0; q < 16; q++) {
        uint4 u4 = xr[q];
        int k = q*8;
        acc += fmaxf(bflo(u4.x) + rb[k+0], 0.0f)*w2[k+0]
             + fmaxf(bfhi(u4.x) + rb[k+1], 0.0f)*w2[k+1]
             + fmaxf(bflo(u4.y) + rb[k+2], 0.0f)*w2[k+2]
             + fmaxf(bfhi(u4.y) + rb[k+3], 0.0f)*w2[k+3]
             + fmaxf(bflo(u4.z) + rb[k+4], 0.0f)*w2[k+4]
             + fmaxf(bfhi(u4.z) + rb[k+5], 0.0f)*w2[k+5]
             + fmaxf(bflo(u4.w) + rb[k+6], 0.0f)*w2[k+6]
             + fmaxf(bfhi(u4.w) + rb[k+7], 0.0f)*w2[k+7];
      }
      lgs[n] = acc;
    }
    __syncthreads();
    float mx = -1e30f;
#pragma unroll
    for (int i = 0; i < 4; i++) mx = fmaxf(mx, lgs[tid + i*256]);
    red[tid] = mx; __syncthreads();
    for (int s = 128; s > 0; s >>= 1) { if (tid < s) red[tid] = fmaxf(red[tid], red[tid+s]); __syncthreads(); }
    float m = red[0]; __syncthreads();
    float sum = 0.0f;
#pragma unroll
    for (int i = 0; i < 4; i++) sum += expf(lgs[tid + i*256] - m);
    red[tid] = sum; __syncthreads();
    for (int s = 128; s > 0; s >>= 1) { if (tid < s) red[tid] += red[tid+s]; __syncthreads(); }
    float inv = 1.0f / red[0];
    __syncthreads();
    ws[tid] = expf(lgs[nch*256 + tid] - m) * inv;
  } else {
    ws[tid] = 1.0f;
  }
  __syncthreads();
  int pu = tid & 127, ng = tid >> 7;
  const unsigned* eb = embh + (size_t)(b*1024 + nch*256 + ng*128)*128 + pu;
  float a0 = 0.0f, a1 = 0.0f;
#pragma unroll 4
  for (int n = 0; n < 128; n++) {
    unsigned u = eb[(size_t)n*128];
    float w = ws[ng*128 + n];
    a0 += w * bflo(u);
    a1 += w * bfhi(u);
  }
  int p = nch*2 + ng;
  pp[((size_t)p*32 + b)*256 + pu*2]     = a0;
  pp[((size_t)p*32 + b)*256 + pu*2 + 1] = a1;
}

// ---------------- fused: pe = scale * sum_p pp ; P[b][o] = pe[b].up_w[o] + up_b[o] ----------------
__global__ __launch_bounds__(256) void k_pool_pgemm(const float* __restrict__ pp,
        const float* __restrict__ up_w, const float* __restrict__ up_b,
        float* __restrict__ Pout, float scale) {
  int wb = blockIdx.x;             // 128 = b(32) x oc(4)
  int b = wb >> 2, oc = wb & 3;
  int tid = threadIdx.x;
  __shared__ float pe[256];
  float s = 0.0f;
#pragma unroll
  for (int p = 0; p < 8; p++) s += pp[((size_t)p*32 + b)*256 + tid];
  pe[tid] = s * scale;
  __syncthreads();
  int o = oc*256 + tid;
  const float* wr = up_w + (size_t)o*256;
  float acc = up_b[o];
#pragma unroll 8
  for (int d = 0; d < 256; d += 4) {
    float4 w4 = *(const float4*)(wr + d);
    acc += w4.x*pe[d] + w4.y*pe[d+1] + w4.z*pe[d+2] + w4.w*pe[d+3];
  }
  Pout[(size_t)b*1024 + o] = acc;
}

// ---------------- final energy ----------------
__global__ void k_out(const float* __restrict__ c, const float* __restrict__ ew,
                      const float* __restrict__ eb, float* __restrict__ out) {
  int b = blockIdx.x, t = threadIdx.x;   // 32 x 64
  float acc = 0.0f;
  for (int d = t; d < 1024; d += 64) acc += c[b*1024 + d] * ew[d];
  for (int off = 32; off > 0; off >>= 1) acc += __shfl_down(acc, off, 64);
  if (t == 0) out[b] = acc + eb[0];
}

extern "C" void kernel_launch(void* const* d_in, const int* in_sizes, int n_in,
                              void* d_out, int out_size, void* d_ws, size_t ws_size,
                              hipStream_t stream) {
  const int*   x_int  = (const int*)d_in[0];
  const float* x_xyz  = (const float*)d_in[1];
  const float* am     = (const float*)d_in[2];
  const float* el     = (const float*)d_in[3];
  const float* po     = (const float*)d_in[4];
  const float* xyz_w  = (const float*)d_in[5];
  const float* xyz_b  = (const float*)d_in[6];
  const float* up_w   = (const float*)d_in[7];
  const float* up_b   = (const float*)d_in[8];
  const float* w_ih   = (const float*)d_in[9];
  const float* w_hh   = (const float*)d_in[10];
  const float* b_ih   = (const float*)d_in[11];
  const float* b_hh   = (const float*)d_in[12];
  const float* att1_w = (const float*)d_in[13];
  const float* att1_b = (const float*)d_in[14];
  const float* att2_w = (const float*)d_in[15];
  const float* att2_b = (const float*)d_in[16];
  const float* en_w   = (const float*)d_in[17];
  const float* en_b   = (const float*)d_in[18];
  float* out = (float*)d_out;

  char* ws = (char*)d_ws;
  size_t off = 0;
  auto alloc = [&](size_t bytes) { void* p = ws + off; off += (bytes + 255) & ~(size_t)255; return p; };
  float*    emb  = (float*)alloc((size_t)BN*256*4);       // 33.6 MB
  unsigned* embh = (unsigned*)alloc((size_t)BN*128*4);    // 16.8 MB (bf16x2)
  unsigned* wt2  = (unsigned*)alloc((size_t)1536*4096*4); // 25.2 MB
  unsigned* xah  = (unsigned*)alloc((size_t)BN*64*4);     // 8.4 MB (bf16x2)
  float*    wcp  = (float*)alloc((size_t)8*128*256*4);    // 1 MB
  float*    wc   = (float*)alloc((size_t)128*256*4);
  float*    bc   = (float*)alloc((size_t)128*4);
  float*    gp   = (float*)alloc((size_t)KS*32*4096*4);   // 12.6 MB
  float*    pp   = (float*)alloc((size_t)8*32*256*4);     // 256 KB
  float*    P    = (float*)alloc((size_t)32*1024*4);
  float*    h    = (float*)alloc((size_t)32*1024*4);
  float*    c    = (float*)alloc((size_t)32*1024*4);
  float*    rap  = (float*)alloc((size_t)4*32*128*4);
  (void)ws_size; (void)in_sizes; (void)n_in; (void)out_size;

  k_zero<<<128, 256, 0, stream>>>(c);
  k_emb<<<BN, 256, 0, stream>>>(x_int, x_xyz, am, el, po, xyz_w, xyz_b, emb, embh);
  k_wt<<<dim3(128, 96), 256, 0, stream>>>(w_ih, w_hh, wt2);
  k_wc1<<<dim3(128, 8), 256, 0, stream>>>(up_w, att1_w, wcp);
  k_wc2<<<128, 256, 0, stream>>>(wcp, wc);
  k_bc<<<128, 64, 0, stream>>>(up_b, att1_w, bc);
  // xah = bf16pack(emb @ wc^T + bc)   (M=32768, K=256, N=128)
  k_gemm32<<<BN/32, 256, 0, stream>>>(emb, wc, bc, xah);
  // P0 = mean path (uniform weights, scale 1/1024 in pgemm)
  k_pool_att<<<128, 256, 0, stream>>>(nullptr, rap, att1_b, att2_w, att2_b, embh, pp);
  k_pool_pgemm<<<128, 256, 0, stream>>>(pp, up_w, up_b, P, 1.0f/1024.0f);

  for (int step = 0; step < 6; step++) {
    int nks = (step == 0) ? 8 : KS;   // h==0 on step 0 -> ks>=8 partials are exactly zero
    k_gates<<<dim3(32, nks), 256, 0, stream>>>(P, h, wt2, gp);
    k_lstm_rap<<<128, 256, 0, stream>>>(gp, b_ih, b_hh, c, h, att1_w, rap,
                                        step < 5 ? 1 : 0, nks);
    if (step < 5) {  // last step's attention output is unused
      k_pool_att<<<128, 256, 0, stream>>>(xah, rap, att1_b, att2_w, att2_b, embh, pp);
      k_pool_pgemm<<<128, 256, 0, stream>>>(pp, up_w, up_b, P, 1.0f);
    }
  }
  k_out<<<32, 64, 0, stream>>>(c, en_w, en_b, out);
}

// Round 12
// 480.440 us; speedup vs baseline: 1.0005x; 1.0005x over previous
//
#include <hip/hip_runtime.h>
#include <math.h>

#define BB 32
#define NN 1024
#define BN (BB*NN)
#define KS 24
#define KCH 128

__device__ __forceinline__ float sigmoidf_(float v) { return 1.0f / (1.0f + expf(-v)); }
__device__ __forceinline__ unsigned f2bf(float f) {           // round-to-nearest-even bf16 bits
  unsigned u = __float_as_uint(f);
  return (u + 0x7fffu + ((u >> 16) & 1u)) >> 16;
}
__device__ __forceinline__ float bflo(unsigned u) { return __uint_as_float(u << 16); }
__device__ __forceinline__ float bfhi(unsigned u) { return __uint_as_float(u & 0xffff0000u); }

// ---------------- zero c ----------------
__global__ void k_zero(float* __restrict__ c) {
  int i = blockIdx.x * 256 + threadIdx.x;
  c[i] = 0.0f;
}

// ---------------- embedding: emb[row][256] fp32 + embh[row][128] packed bf16x2 ----------------
__global__ void k_emb(const int* __restrict__ xint, const float* __restrict__ xyz,
                      const float* __restrict__ am, const float* __restrict__ el,
                      const float* __restrict__ po, const float* __restrict__ xw,
                      const float* __restrict__ xb, float* __restrict__ emb,
                      unsigned* __restrict__ embh) {
  __shared__ float sv[256];
  int row = blockIdx.x;
  int d = threadIdx.x;
  int i0 = xint[row*3+0], i1 = xint[row*3+1], i2 = xint[row*3+2];
  float v;
  if (d < 28)        v = am[i0*28 + d];
  else if (d < 56)   v = el[i1*28 + (d-28)];
  else if (d < 84)   v = po[i2*28 + (d-56)];
  else {
    int o = d - 84;
    float x0 = xyz[row*3+0], x1 = xyz[row*3+1], x2 = xyz[row*3+2];
    v = fmaxf(xw[o*3+0]*x0 + xw[o*3+1]*x1 + xw[o*3+2]*x2 + xb[o], 0.0f);
  }
  emb[(size_t)row*256 + d] = v;
  sv[d] = v;
  __syncthreads();
  if (d < 128) {
    unsigned u = (f2bf(sv[d*2+1]) << 16) | f2bf(sv[d*2]);
    embh[(size_t)row*128 + d] = u;
  }
}

// ---------------- transpose+quantize weights: wt2[k2][j] = pack(bf16 w[2k2][j], bf16 w[2k2+1][j]) ----------------
__global__ __launch_bounds__(256) void k_wt(const float* __restrict__ w_ih,
        const float* __restrict__ w_hh, unsigned* __restrict__ wt2) {
  __shared__ float t[32][33];
  int jt = blockIdx.x * 32, kt = blockIdx.y * 32;
  int tx = threadIdx.x & 31, ty = threadIdx.x >> 5;   // ty 0..7
#pragma unroll
  for (int i = 0; i < 4; i++) {
    int j = jt + ty + i*8;
    int k = kt + tx;
    float v = (k < 2048) ? w_ih[(size_t)j*2048 + k] : w_hh[(size_t)j*1024 + (k - 2048)];
    t[ty + i*8][tx] = v;                              // t[j_local][k_local]
  }
  __syncthreads();
#pragma unroll
  for (int i = 0; i < 2; i++) {
    int kl2 = ty + i*8;                               // 0..15
    float lo = t[tx][kl2*2], hi = t[tx][kl2*2+1];
    unsigned u = (f2bf(hi) << 16) | f2bf(lo);
    wt2[(size_t)((kt >> 1) + kl2)*4096 + jt + tx] = u;
  }
}

// ---------------- Wc partials: wcp[och][k][d] ----------------
__global__ void k_wc1(const float* __restrict__ up_w, const float* __restrict__ att1w,
                      float* __restrict__ wcp) {
  int k = blockIdx.x;       // 128
  int och = blockIdx.y;     // 8
  int d = threadIdx.x;      // 256
  __shared__ float s[128];
  int o0 = och*128;
  if (d < 128) s[d] = att1w[(size_t)k*2048 + 1024 + o0 + d];
  __syncthreads();
  float acc = 0.0f;
#pragma unroll 8
  for (int oi = 0; oi < 128; oi++) acc += up_w[(size_t)(o0+oi)*256 + d] * s[oi];
  wcp[((size_t)och*128 + k)*256 + d] = acc;
}

__global__ void k_wc2(const float* __restrict__ wcp, float* __restrict__ wc) {
  int k = blockIdx.x, d = threadIdx.x;
  float s = 0.0f;
#pragma unroll
  for (int p = 0; p < 8; p++) s += wcp[((size_t)p*128 + k)*256 + d];
  wc[k*256 + d] = s;
}

// ---------------- bc[k] = sum_o up_b[o] * att1_w[k][1024+o] ----------------
__global__ void k_bc(const float* __restrict__ up_b, const float* __restrict__ att1w,
                     float* __restrict__ bc) {
  int k = blockIdx.x;   // 128 blocks x 64 threads
  int t = threadIdx.x;
  float acc = 0.0f;
#pragma unroll
  for (int i = 0; i < 4; i++) {
    int o = i*256 + t*4;
    float4 a4 = *(const float4*)(att1w + (size_t)k*2048 + 1024 + o);
    float4 b4 = *(const float4*)(up_b + o);
    acc += a4.x*b4.x + a4.y*b4.y + a4.z*b4.z + a4.w*b4.w;
  }
#pragma unroll
  for (int m = 32; m >= 1; m >>= 1) acc += __shfl_xor(acc, m, 64);
  if (t == 0) bc[k] = acc;
}

// ---------------- fp32 GEMM 32x128 tile, BK=32: xah = bf16pack(emb @ wc^T + bc) ----------------
__global__ __launch_bounds__(256) void k_gemm32(const float* __restrict__ A,
        const float* __restrict__ W, const float* __restrict__ bias,
        unsigned* __restrict__ Ch) {
  __shared__ float As[32][33];
  __shared__ float Bs[32][133];     // 4*133 = 532 = 20 mod 32 -> conflict-free kq spread
  const int m0 = blockIdx.x * 32;
  const int tid = threadIdx.x;
  const int tx = tid & 15, ty = tid >> 4;
  float acc[2][8];
#pragma unroll
  for (int i = 0; i < 2; i++)
#pragma unroll
    for (int j = 0; j < 8; j++) acc[i][j] = 0.0f;

  for (int kt = 0; kt < 256; kt += 32) {
    {
      int r = tid >> 3;               // 0..31
      int kq = (tid & 7) * 4;         // 0..28
      float4 a4 = *(const float4*)(A + (size_t)(m0 + r)*256 + kt + kq);
      As[kq+0][r] = a4.x; As[kq+1][r] = a4.y; As[kq+2][r] = a4.z; As[kq+3][r] = a4.w;
    }
#pragma unroll
    for (int i = 0; i < 4; i++) {
      int s = tid + i*256;            // 0..1023
      int n = s >> 3;                 // 0..127
      int kq = (s & 7) * 4;
      float4 b4 = *(const float4*)(W + (size_t)n*256 + kt + kq);
      Bs[kq+0][n] = b4.x; Bs[kq+1][n] = b4.y; Bs[kq+2][n] = b4.z; Bs[kq+3][n] = b4.w;
    }
    __syncthreads();
#pragma unroll
    for (int kk = 0; kk < 32; kk++) {
      float a0 = As[kk][ty*2], a1 = As[kk][ty*2+1];
      float4 b0 = *(const float4*)&Bs[kk][tx*4];
      float4 b1 = *(const float4*)&Bs[kk][64 + tx*4];
      float bv[8] = {b0.x,b0.y,b0.z,b0.w,b1.x,b1.y,b1.z,b1.w};
#pragma unroll
      for (int j = 0; j < 8; j++) { acc[0][j] += a0*bv[j]; acc[1][j] += a1*bv[j]; }
    }
    __syncthreads();
  }
#pragma unroll
  for (int i = 0; i < 2; i++) {
    int row = m0 + ty*2 + i;
#pragma unroll
    for (int ch = 0; ch < 2; ch++) {
      int col = ch*64 + tx*4;
      float c0 = acc[i][ch*4+0] + bias[col+0];
      float c1 = acc[i][ch*4+1] + bias[col+1];
      float c2 = acc[i][ch*4+2] + bias[col+2];
      float c3 = acc[i][ch*4+3] + bias[col+3];
      uint2 o;
      o.x = (f2bf(c1) << 16) | f2bf(c0);
      o.y = (f2bf(c3) << 16) | f2bf(c2);
      *(uint2*)(Ch + (size_t)row*64 + col/2) = o;
    }
  }
}

// ---------------- gates partials over bf16-packed transposed weights ----------------
// grid (32 jb, nks); block 256; each block: 128 j x 32 b for one 128-k slice
__global__ __launch_bounds__(256) void k_gates(const float* __restrict__ P, const float* __restrict__ h,
        const unsigned* __restrict__ wt2, float* __restrict__ gp) {
  __shared__ float Xs[32][KCH];     // 16 KB
  int jb = blockIdx.x;              // 0..31
  int ks = blockIdx.y;              // 0..nks-1
  int tid = threadIdx.x;
  int kglob = ks * KCH;
  const float* src; int soff;
  if (ks < 8)       { src = P; soff = kglob; }
  else if (ks < 16) { src = h; soff = kglob - 1024; }
  else              { src = h; soff = kglob - 2048; }
#pragma unroll
  for (int i = 0; i < 4; i++) {
    int s = tid + i*256;            // float4 idx 0..1023
    int b = s >> 5, k4 = s & 31;
    *(float4*)&Xs[b][k4*4] = *(const float4*)(src + b*1024 + soff + k4*4);
  }
  __syncthreads();

  int jg = tid & 31, bg = tid >> 5;        // 32 j-groups x 8 b-groups
  int j0 = jb*128 + jg*4;
  int b0 = bg*4;
  const unsigned* wr = wt2 + (size_t)(ks*64)*4096 + j0;
  float acc[4][4];
#pragma unroll
  for (int i = 0; i < 4; i++)
#pragma unroll
    for (int j = 0; j < 4; j++) acc[i][j] = 0.0f;

  for (int k2 = 0; k2 < KCH/2; k2++) {
    uint4 u4 = *(const uint4*)(wr + (size_t)k2*4096);
    float wlo[4], whi[4];
    wlo[0] = bflo(u4.x); whi[0] = bfhi(u4.x);
    wlo[1] = bflo(u4.y); whi[1] = bfhi(u4.y);
    wlo[2] = bflo(u4.z); whi[2] = bfhi(u4.z);
    wlo[3] = bflo(u4.w); whi[3] = bfhi(u4.w);
    int k = k2*2;
#pragma unroll
    for (int bi = 0; bi < 4; bi++) {
      float x0 = Xs[b0+bi][k], x1 = Xs[b0+bi][k+1];
#pragma unroll
      for (int ji = 0; ji < 4; ji++) acc[ji][bi] += wlo[ji]*x0 + whi[ji]*x1;
    }
  }
#pragma unroll
  for (int bi = 0; bi < 4; bi++) {
    float4 v = make_float4(acc[0][bi], acc[1][bi], acc[2][bi], acc[3][bi]);
    *(float4*)(gp + ((size_t)ks*32 + b0 + bi)*4096 + j0) = v;
  }
}

// ---------------- reduce gates (nks partials) + LSTM cell + ra partials per dch ----------------
__global__ __launch_bounds__(256) void k_lstm_rap(const float* __restrict__ gp,
        const float* __restrict__ b_ih, const float* __restrict__ b_hh,
        float* __restrict__ c, float* __restrict__ h,
        const float* __restrict__ att1w, float* __restrict__ rap,
        int need_ra, int nks) {
  int wb = blockIdx.x;             // 128 = b(32) x dch(4)
  int b = wb >> 2, dch = wb & 3;
  int tid = threadIdx.x;
  int d = dch*256 + tid;
  __shared__ float hs[256];
  float gi = b_ih[d]        + b_hh[d];
  float gf = b_ih[1024 + d] + b_hh[1024 + d];
  float gg = b_ih[2048 + d] + b_hh[2048 + d];
  float go = b_ih[3072 + d] + b_hh[3072 + d];
#pragma unroll 4
  for (int ks = 0; ks < nks; ks++) {
    const float* base = gp + ((size_t)ks*32 + b)*4096;
    gi += base[d]; gf += base[1024 + d]; gg += base[2048 + d]; go += base[3072 + d];
  }
  size_t ci = (size_t)b*1024 + d;
  float cn = sigmoidf_(gf)*c[ci] + sigmoidf_(gi)*tanhf(gg);
  c[ci] = cn;
  float hn = sigmoidf_(go)*tanhf(cn);
  h[ci] = hn;
  hs[tid] = hn;
  __syncthreads();
  if (need_ra) {
    int k = tid >> 1, half = tid & 1;
    const float* wr = att1w + (size_t)k*2048 + dch*256 + half*128;
    float acc = 0.0f;
#pragma unroll 8
    for (int i = 0; i < 32; i++) {
      float4 w4 = *(const float4*)(wr + i*4);
      int dl = half*128 + i*4;
      acc += w4.x*hs[dl] + w4.y*hs[dl+1] + w4.z*hs[dl+2] + w4.w*hs[dl+3];
    }
    acc += __shfl_xor(acc, 1, 64);
    if (half == 0) rap[((size_t)dch*32 + b)*128 + k] = acc;
  }
}

// ---------------- fused logits + softmax + pooled bf16-emb partials ----------------
// 128 blocks = b(32) x nch(4). xah==nullptr -> uniform weights (initial mean).
__global__ __launch_bounds__(256) void k_pool_att(const unsigned* __restrict__ xah,
        const float* __restrict__ rap, const float* __restrict__ att1b,
        const float* __restrict__ att2w, const float* __restrict__ att2b,
        const unsigned* __restrict__ embh, float* __restrict__ pp) {
  int wb = blockIdx.x;
  int b = wb >> 2, nch = wb & 3;
  int tid = threadIdx.x;
  __shared__ float rb[128], w2[128];
  __shared__ float lgs[1024];
  __shared__ float red[256];
  __shared__ float ws[256];
  if (xah) {
    if (tid < 128) {
      float r = rap[(size_t)(0  + b)*128 + tid] + rap[(size_t)(32 + b)*128 + tid]
              + rap[(size_t)(64 + b)*128 + tid] + rap[(size_t)(96 + b)*128 + tid];
      rb[tid] = r + att1b[tid];
      w2[tid] = att2w[tid];
    }
    __syncthreads();
    float a2b = att2b[0];
#pragma unroll
    for (int i = 0; i < 4; i++) {
      int n = tid + i*256;
      const uint4* xr = (const uint4*)(xah + ((size_t)b*1024 + n)*64);
      float acc = a2b;
#pragma unroll 4
      for (int q = 0; q < 16; q++) {
        uint4 u4 = xr[q];
        int k = q*8;
        acc += fmaxf(bflo(u4.x) + rb[k+0], 0.0f)*w2[k+0]
             + fmaxf(bfhi(u4.x) + rb[k+1], 0.0f)*w2[k+1]
             + fmaxf(bflo(u4.y) + rb[k+2], 0.0f)*w2[k+2]
             + fmaxf(bfhi(u4.y) + rb[k+3], 0.0f)*w2[k+3]
             + fmaxf(bflo(u4.z) + rb[k+4], 0.0f)*w2[k+4]
             + fmaxf(bfhi(u4.z) + rb[k+5], 0.0f)*w2[k+5]
             + fmaxf(bflo(u4.w) + rb[k+6], 0.0f)*w2[k+6]
             + fmaxf(bfhi(u4.w) + rb[k+7], 0.0f)*w2[k+7];
      }
      lgs[n] = acc;
    }
    __syncthreads();
    float mx = -1e30f;
#pragma unroll
    for (int i = 0; i < 4; i++) mx = fmaxf(mx, lgs[tid + i*256]);
    red[tid] = mx; __syncthreads();
    for (int s = 128; s > 0; s >>= 1) { if (tid < s) red[tid] = fmaxf(red[tid], red[tid+s]); __syncthreads(); }
    float m = red[0]; __syncthreads();
    float sum = 0.0f;
#pragma unroll
    for (int i = 0; i < 4; i++) sum += expf(lgs[tid + i*256] - m);
    red[tid] = sum; __syncthreads();
    for (int s = 128; s > 0; s >>= 1) { if (tid < s) red[tid] += red[tid+s]; __syncthreads(); }
    float inv = 1.0f / red[0];
    __syncthreads();
    ws[tid] = expf(lgs[nch*256 + tid] - m) * inv;
  } else {
    ws[tid] = 1.0f;
  }
  __syncthreads();
  int pu = tid & 127, ng = tid >> 7;
  const unsigned* eb = embh + (size_t)(b*1024 + nch*256 + ng*128)*128 + pu;
  float a0 = 0.0f, a1 = 0.0f;
#pragma unroll 4
  for (int n = 0; n < 128; n++) {
    unsigned u = eb[(size_t)n*128];
    float w = ws[ng*128 + n];
    a0 += w * bflo(u);
    a1 += w * bfhi(u);
  }
  int p = nch*2 + ng;
  pp[((size_t)p*32 + b)*256 + pu*2]     = a0;
  pp[((size_t)p*32 + b)*256 + pu*2 + 1] = a1;
}

// ---------------- fused: pe = scale * sum_p pp ; P[b][o] = pe[b].up_w[o] + up_b[o] ----------------
__global__ __launch_bounds__(256) void k_pool_pgemm(const float* __restrict__ pp,
        const float* __restrict__ up_w, const float* __restrict__ up_b,
        float* __restrict__ Pout, float scale) {
  int wb = blockIdx.x;             // 128 = b(32) x oc(4)
  int b = wb >> 2, oc = wb & 3;
  int tid = threadIdx.x;
  __shared__ float pe[256];
  float s = 0.0f;
#pragma unroll
  for (int p = 0; p < 8; p++) s += pp[((size_t)p*32 + b)*256 + tid];
  pe[tid] = s * scale;
  __syncthreads();
  int o = oc*256 + tid;
  const float* wr = up_w + (size_t)o*256;
  float acc = up_b[o];
#pragma unroll 8
  for (int d = 0; d < 256; d += 4) {
    float4 w4 = *(const float4*)(wr + d);
    acc += w4.x*pe[d] + w4.y*pe[d+1] + w4.z*pe[d+2] + w4.w*pe[d+3];
  }
  Pout[(size_t)b*1024 + o] = acc;
}

// ---------------- final energy ----------------
__global__ void k_out(const float* __restrict__ c, const float* __restrict__ ew,
                      const float* __restrict__ eb, float* __restrict__ out) {
  int b = blockIdx.x, t = threadIdx.x;   // 32 x 64
  float acc = 0.0f;
  for (int d = t; d < 1024; d += 64) acc += c[b*1024 + d] * ew[d];
  for (int off = 32; off > 0; off >>= 1) acc += __shfl_down(acc, off, 64);
  if (t == 0) out[b] = acc + eb[0];
}

extern "C" void kernel_launch(void* const* d_in, const int* in_sizes, int n_in,
                              void* d_out, int out_size, void* d_ws, size_t ws_size,
                              hipStream_t stream) {
  const int*   x_int  = (const int*)d_in[0];
  const float* x_xyz  = (const float*)d_in[1];
  const float* am     = (const float*)d_in[2];
  const float* el     = (const float*)d_in[3];
  const float* po     = (const float*)d_in[4];
  const float* xyz_w  = (const float*)d_in[5];
  const float* xyz_b  = (const float*)d_in[6];
  const float* up_w   = (const float*)d_in[7];
  const float* up_b   = (const float*)d_in[8];
  const float* w_ih   = (const float*)d_in[9];
  const float* w_hh   = (const float*)d_in[10];
  const float* b_ih   = (const float*)d_in[11];
  const float* b_hh   = (const float*)d_in[12];
  const float* att1_w = (const float*)d_in[13];
  const float* att1_b = (const float*)d_in[14];
  const float* att2_w = (const float*)d_in[15];
  const float* att2_b = (const float*)d_in[16];
  const float* en_w   = (const float*)d_in[17];
  const float* en_b   = (const float*)d_in[18];
  float* out = (float*)d_out;

  char* ws = (char*)d_ws;
  size_t off = 0;
  auto alloc = [&](size_t bytes) { void* p = ws + off; off += (bytes + 255) & ~(size_t)255; return p; };
  float*    emb  = (float*)alloc((size_t)BN*256*4);       // 33.6 MB
  unsigned* embh = (unsigned*)alloc((size_t)BN*128*4);    // 16.8 MB (bf16x2)
  unsigned* wt2  = (unsigned*)alloc((size_t)1536*4096*4); // 25.2 MB
  unsigned* xah  = (unsigned*)alloc((size_t)BN*64*4);     // 8.4 MB (bf16x2)
  float*    wcp  = (float*)alloc((size_t)8*128*256*4);    // 1 MB
  float*    wc   = (float*)alloc((size_t)128*256*4);
  float*    bc   = (float*)alloc((size_t)128*4);
  float*    gp   = (float*)alloc((size_t)KS*32*4096*4);   // 12.6 MB
  float*    pp   = (float*)alloc((size_t)8*32*256*4);     // 256 KB
  float*    P    = (float*)alloc((size_t)32*1024*4);
  float*    h    = (float*)alloc((size_t)32*1024*4);
  float*    c    = (float*)alloc((size_t)32*1024*4);
  float*    rap  = (float*)alloc((size_t)4*32*128*4);
  (void)ws_size; (void)in_sizes; (void)n_in; (void)out_size;

  k_zero<<<128, 256, 0, stream>>>(c);
  k_emb<<<BN, 256, 0, stream>>>(x_int, x_xyz, am, el, po, xyz_w, xyz_b, emb, embh);
  k_wt<<<dim3(128, 96), 256, 0, stream>>>(w_ih, w_hh, wt2);
  k_wc1<<<dim3(128, 8), 256, 0, stream>>>(up_w, att1_w, wcp);
  k_wc2<<<128, 256, 0, stream>>>(wcp, wc);
  k_bc<<<128, 64, 0, stream>>>(up_b, att1_w, bc);
  // xah = bf16pack(emb @ wc^T + bc)   (M=32768, K=256, N=128)
  k_gemm32<<<BN/32, 256, 0, stream>>>(emb, wc, bc, xah);
  // P0 = mean path (uniform weights, scale 1/1024 in pgemm)
  k_pool_att<<<128, 256, 0, stream>>>(nullptr, rap, att1_b, att2_w, att2_b, embh, pp);
  k_pool_pgemm<<<128, 256, 0, stream>>>(pp, up_w, up_b, P, 1.0f/1024.0f);

  for (int step = 0; step < 6; step++) {
    int nks = (step == 0) ? 8 : KS;   // h==0 on step 0 -> ks>=8 partials are exactly zero
    k_gates<<<dim3(32, nks), 256, 0, stream>>>(P, h, wt2, gp);
    k_lstm_rap<<<128, 256, 0, stream>>>(gp, b_ih, b_hh, c, h, att1_w, rap,
                                        step < 5 ? 1 : 0, nks);
    if (step < 5) {  // last step's attention output is unused
      k_pool_att<<<128, 256, 0, stream>>>(xah, rap, att1_b, att2_w, att2_b, embh, pp);
      k_pool_pgemm<<<128, 256, 0, stream>>>(pp, up_w, up_b, P, 1.0f);
    }
  }
  k_out<<<32, 64, 0, stream>>>(c, en_w, en_b, out);
}

// Round 13
// 429.851 us; speedup vs baseline: 1.1183x; 1.1177x over previous
//
#include <hip/hip_runtime.h>
#include <math.h>

#define BB 32
#define NN 1024
#define BN (BB*NN)
#define KS 24
#define KCH 128

using bf16x8 = __attribute__((ext_vector_type(8))) short;   // 8 bf16 (4 VGPRs)
using f32x4  = __attribute__((ext_vector_type(4))) float;   // 4 fp32 acc

__device__ __forceinline__ float sigmoidf_(float v) { return 1.0f / (1.0f + expf(-v)); }
__device__ __forceinline__ unsigned f2bf(float f) {           // round-to-nearest-even bf16 bits
  unsigned u = __float_as_uint(f);
  return (u + 0x7fffu + ((u >> 16) & 1u)) >> 16;
}
__device__ __forceinline__ float bflo(unsigned u) { return __uint_as_float(u << 16); }
__device__ __forceinline__ float bfhi(unsigned u) { return __uint_as_float(u & 0xffff0000u); }

// ---------------- zero c (h is written before first read: step0 gates skip h) ----------------
__global__ void k_zero(float* __restrict__ c) {
  int i = blockIdx.x * 256 + threadIdx.x;
  c[i] = 0.0f;
}

// ---------------- embedding: embh/embl [row][128] packed bf16x2 (hi + residual lo) ----------------
__global__ void k_emb(const int* __restrict__ xint, const float* __restrict__ xyz,
                      const float* __restrict__ am, const float* __restrict__ el,
                      const float* __restrict__ po, const float* __restrict__ xw,
                      const float* __restrict__ xb,
                      unsigned* __restrict__ embh, unsigned* __restrict__ embl) {
  __shared__ float sv[256];
  int row = blockIdx.x;
  int d = threadIdx.x;
  int i0 = xint[row*3+0], i1 = xint[row*3+1], i2 = xint[row*3+2];
  float v;
  if (d < 28)        v = am[i0*28 + d];
  else if (d < 56)   v = el[i1*28 + (d-28)];
  else if (d < 84)   v = po[i2*28 + (d-56)];
  else {
    int o = d - 84;
    float x0 = xyz[row*3+0], x1 = xyz[row*3+1], x2 = xyz[row*3+2];
    v = fmaxf(xw[o*3+0]*x0 + xw[o*3+1]*x1 + xw[o*3+2]*x2 + xb[o], 0.0f);
  }
  sv[d] = v;
  __syncthreads();
  if (d < 128) {
    float v0 = sv[d*2], v1 = sv[d*2+1];
    unsigned h0 = f2bf(v0), h1 = f2bf(v1);
    embh[(size_t)row*128 + d] = (h1 << 16) | h0;
    float l0 = v0 - __uint_as_float(h0 << 16);
    float l1 = v1 - __uint_as_float(h1 << 16);
    embl[(size_t)row*128 + d] = (f2bf(l1) << 16) | f2bf(l0);
  }
}

// ---------------- transpose+quantize weights: wt2[k2][j] = pack(bf16 w[2k2][j], bf16 w[2k2+1][j]) ----------------
__global__ __launch_bounds__(256) void k_wt(const float* __restrict__ w_ih,
        const float* __restrict__ w_hh, unsigned* __restrict__ wt2) {
  __shared__ float t[32][33];
  int jt = blockIdx.x * 32, kt = blockIdx.y * 32;
  int tx = threadIdx.x & 31, ty = threadIdx.x >> 5;   // ty 0..7
#pragma unroll
  for (int i = 0; i < 4; i++) {
    int j = jt + ty + i*8;
    int k = kt + tx;
    float v = (k < 2048) ? w_ih[(size_t)j*2048 + k] : w_hh[(size_t)j*1024 + (k - 2048)];
    t[ty + i*8][tx] = v;                              // t[j_local][k_local]
  }
  __syncthreads();
#pragma unroll
  for (int i = 0; i < 2; i++) {
    int kl2 = ty + i*8;                               // 0..15
    float lo = t[tx][kl2*2], hi = t[tx][kl2*2+1];
    unsigned u = (f2bf(hi) << 16) | f2bf(lo);
    wt2[(size_t)((kt >> 1) + kl2)*4096 + jt + tx] = u;
  }
}

// ---------------- Wc partials: wcp[och][n][d] ----------------
__global__ void k_wc1(const float* __restrict__ up_w, const float* __restrict__ att1w,
                      float* __restrict__ wcp) {
  int k = blockIdx.x;       // 128 (n index)
  int och = blockIdx.y;     // 8
  int d = threadIdx.x;      // 256
  __shared__ float s[128];
  int o0 = och*128;
  if (d < 128) s[d] = att1w[(size_t)k*2048 + 1024 + o0 + d];
  __syncthreads();
  float acc = 0.0f;
#pragma unroll 8
  for (int oi = 0; oi < 128; oi++) acc += up_w[(size_t)(o0+oi)*256 + d] * s[oi];
  wcp[((size_t)och*128 + k)*256 + d] = acc;
}

// ---------------- reduce wcp -> packed bf16 hi/lo wchh/wchl [n][128] ----------------
__global__ void k_wc2(const float* __restrict__ wcp, unsigned* __restrict__ wchh,
                      unsigned* __restrict__ wchl) {
  __shared__ float sv[256];
  int n = blockIdx.x, d = threadIdx.x;
  float s = 0.0f;
#pragma unroll
  for (int p = 0; p < 8; p++) s += wcp[((size_t)p*128 + n)*256 + d];
  sv[d] = s;
  __syncthreads();
  if (d < 128) {
    float v0 = sv[d*2], v1 = sv[d*2+1];
    unsigned h0 = f2bf(v0), h1 = f2bf(v1);
    wchh[n*128 + d] = (h1 << 16) | h0;
    float l0 = v0 - __uint_as_float(h0 << 16);
    float l1 = v1 - __uint_as_float(h1 << 16);
    wchl[n*128 + d] = (f2bf(l1) << 16) | f2bf(l0);
  }
}

// ---------------- bc[k] = sum_o up_b[o] * att1_w[k][1024+o] ----------------
__global__ void k_bc(const float* __restrict__ up_b, const float* __restrict__ att1w,
                     float* __restrict__ bc) {
  int k = blockIdx.x;   // 128 blocks x 64 threads
  int t = threadIdx.x;
  float acc = 0.0f;
#pragma unroll
  for (int i = 0; i < 4; i++) {
    int o = i*256 + t*4;
    float4 a4 = *(const float4*)(att1w + (size_t)k*2048 + 1024 + o);
    float4 b4 = *(const float4*)(up_b + o);
    acc += a4.x*b4.x + a4.y*b4.y + a4.z*b4.z + a4.w*b4.w;
  }
#pragma unroll
  for (int m = 32; m >= 1; m >>= 1) acc += __shfl_xor(acc, m, 64);
  if (t == 0) bc[k] = acc;
}

// ---------------- MFMA GEMM: xa[m][n] = sum_k emb[m][k]*wc[n][k] + bc[n] ----------------
// 3-term hi/lo split (~fp32 accuracy). 1024 blocks x 4 waves; wave = 16x64 tile.
// A frag: lane l -> row m0+(l&15), k = k0 + (l>>4)*8 .. +7 (contiguous, 16B load)
// B frag: lane l -> col n (reads wc row n), same k slice. C/D: col=l&15, row=(l>>4)*4+reg.
__global__ __launch_bounds__(256) void k_gemm_mfma(
    const unsigned* __restrict__ Ahp, const unsigned* __restrict__ Alp,
    const unsigned* __restrict__ Bhp, const unsigned* __restrict__ Blp,
    const float* __restrict__ bias, float* __restrict__ C) {
  const short* Ah = (const short*)Ahp;
  const short* Al = (const short*)Alp;
  const short* Bh = (const short*)Bhp;
  const short* Bl = (const short*)Blp;
  int tid = threadIdx.x;
  int wid = tid >> 6, l = tid & 63;
  int m0 = blockIdx.x*32 + (wid >> 1)*16;
  int n0 = (wid & 1)*64;
  int kb = (l >> 4)*8;                 // 0,8,16,24
  int row = m0 + (l & 15);
  f32x4 acc0 = {0,0,0,0}, acc1 = {0,0,0,0}, acc2 = {0,0,0,0}, acc3 = {0,0,0,0};
  const short* arh = Ah + (size_t)row*256 + kb;
  const short* arl = Al + (size_t)row*256 + kb;
  int ncol = n0 + (l & 15);
  const short* brh = Bh + (size_t)ncol*256 + kb;
  const short* brl = Bl + (size_t)ncol*256 + kb;
#pragma unroll
  for (int k0 = 0; k0 < 256; k0 += 32) {
    bf16x8 ah = *(const bf16x8*)(arh + k0);
    bf16x8 al = *(const bf16x8*)(arl + k0);
#pragma unroll
    for (int nt = 0; nt < 4; nt++) {
      bf16x8 bh = *(const bf16x8*)(brh + (size_t)nt*16*256 + k0);
      bf16x8 bl = *(const bf16x8*)(brl + (size_t)nt*16*256 + k0);
      f32x4 a = (nt == 0) ? acc0 : (nt == 1) ? acc1 : (nt == 2) ? acc2 : acc3;
      a = __builtin_amdgcn_mfma_f32_16x16x32_bf16(ah, bh, a, 0, 0, 0);
      a = __builtin_amdgcn_mfma_f32_16x16x32_bf16(al, bh, a, 0, 0, 0);
      a = __builtin_amdgcn_mfma_f32_16x16x32_bf16(ah, bl, a, 0, 0, 0);
      if (nt == 0) acc0 = a; else if (nt == 1) acc1 = a; else if (nt == 2) acc2 = a; else acc3 = a;
    }
  }
  int r0 = m0 + (l >> 4)*4;
#pragma unroll
  for (int nt = 0; nt < 4; nt++) {
    f32x4 a = (nt == 0) ? acc0 : (nt == 1) ? acc1 : (nt == 2) ? acc2 : acc3;
    int col = n0 + nt*16 + (l & 15);
    float bv = bias[col];
#pragma unroll
    for (int i = 0; i < 4; i++)
      C[(size_t)(r0 + i)*128 + col] = a[i] + bv;
  }
}

// ---------------- gates partials over bf16-packed transposed weights ----------------
// grid (32 jb, nks); block 256; each block: 128 j x 32 b for one 128-k slice
__global__ __launch_bounds__(256) void k_gates(const float* __restrict__ P, const float* __restrict__ h,
        const unsigned* __restrict__ wt2, float* __restrict__ gp) {
  __shared__ float Xs[32][KCH];     // 16 KB
  int jb = blockIdx.x;              // 0..31
  int ks = blockIdx.y;              // 0..nks-1
  int tid = threadIdx.x;
  int kglob = ks * KCH;
  const float* src; int soff;
  if (ks < 8)       { src = P; soff = kglob; }
  else if (ks < 16) { src = h; soff = kglob - 1024; }
  else              { src = h; soff = kglob - 2048; }
#pragma unroll
  for (int i = 0; i < 4; i++) {
    int s = tid + i*256;            // float4 idx 0..1023
    int b = s >> 5, k4 = s & 31;
    *(float4*)&Xs[b][k4*4] = *(const float4*)(src + b*1024 + soff + k4*4);
  }
  __syncthreads();

  int jg = tid & 31, bg = tid >> 5;        // 32 j-groups x 8 b-groups
  int j0 = jb*128 + jg*4;
  int b0 = bg*4;
  const unsigned* wr = wt2 + (size_t)(ks*64)*4096 + j0;
  float acc[4][4];
#pragma unroll
  for (int i = 0; i < 4; i++)
#pragma unroll
    for (int j = 0; j < 4; j++) acc[i][j] = 0.0f;

  for (int k2 = 0; k2 < KCH/2; k2++) {
    uint4 u4 = *(const uint4*)(wr + (size_t)k2*4096);
    float wlo[4], whi[4];
    wlo[0] = bflo(u4.x); whi[0] = bfhi(u4.x);
    wlo[1] = bflo(u4.y); whi[1] = bfhi(u4.y);
    wlo[2] = bflo(u4.z); whi[2] = bfhi(u4.z);
    wlo[3] = bflo(u4.w); whi[3] = bfhi(u4.w);
    int k = k2*2;
#pragma unroll
    for (int bi = 0; bi < 4; bi++) {
      float x0 = Xs[b0+bi][k], x1 = Xs[b0+bi][k+1];
#pragma unroll
      for (int ji = 0; ji < 4; ji++) acc[ji][bi] += wlo[ji]*x0 + whi[ji]*x1;
    }
  }
#pragma unroll
  for (int bi = 0; bi < 4; bi++) {
    float4 v = make_float4(acc[0][bi], acc[1][bi], acc[2][bi], acc[3][bi]);
    *(float4*)(gp + ((size_t)ks*32 + b0 + bi)*4096 + j0) = v;
  }
}

// ---------------- reduce gates (nks partials) + LSTM cell + ra partials per dch ----------------
__global__ __launch_bounds__(256) void k_lstm_rap(const float* __restrict__ gp,
        const float* __restrict__ b_ih, const float* __restrict__ b_hh,
        float* __restrict__ c, float* __restrict__ h,
        const float* __restrict__ att1w, float* __restrict__ rap,
        int need_ra, int nks) {
  int wb = blockIdx.x;             // 128 = b(32) x dch(4)
  int b = wb >> 2, dch = wb & 3;
  int tid = threadIdx.x;
  int d = dch*256 + tid;
  __shared__ float hs[256];
  float gi = b_ih[d]        + b_hh[d];
  float gf = b_ih[1024 + d] + b_hh[1024 + d];
  float gg = b_ih[2048 + d] + b_hh[2048 + d];
  float go = b_ih[3072 + d] + b_hh[3072 + d];
#pragma unroll 4
  for (int ks = 0; ks < nks; ks++) {
    const float* base = gp + ((size_t)ks*32 + b)*4096;
    gi += base[d]; gf += base[1024 + d]; gg += base[2048 + d]; go += base[3072 + d];
  }
  size_t ci = (size_t)b*1024 + d;
  float cn = sigmoidf_(gf)*c[ci] + sigmoidf_(gi)*tanhf(gg);
  c[ci] = cn;
  float hn = sigmoidf_(go)*tanhf(cn);
  h[ci] = hn;
  hs[tid] = hn;
  __syncthreads();
  if (need_ra) {
    int k = tid >> 1, half = tid & 1;
    const float* wr = att1w + (size_t)k*2048 + dch*256 + half*128;
    float acc = 0.0f;
#pragma unroll 8
    for (int i = 0; i < 32; i++) {
      float4 w4 = *(const float4*)(wr + i*4);
      int dl = half*128 + i*4;
      acc += w4.x*hs[dl] + w4.y*hs[dl+1] + w4.z*hs[dl+2] + w4.w*hs[dl+3];
    }
    acc += __shfl_xor(acc, 1, 64);
    if (half == 0) rap[((size_t)dch*32 + b)*128 + k] = acc;
  }
}

// ---------------- logits[b][n] from xa + rap partials, grid (32 b, 8 nc) ----------------
__global__ __launch_bounds__(256) void k_logits(const float* __restrict__ xa,
        const float* __restrict__ rap, const float* __restrict__ att1b,
        const float* __restrict__ att2w, const float* __restrict__ att2b,
        float* __restrict__ lg) {
  int b = blockIdx.x, nc = blockIdx.y;
  int t = threadIdx.x;
  __shared__ float rb[128], w2[128];
  if (t < 128) {
    float r = rap[(size_t)(0  + b)*128 + t] + rap[(size_t)(32 + b)*128 + t]
            + rap[(size_t)(64 + b)*128 + t] + rap[(size_t)(96 + b)*128 + t];
    rb[t] = r + att1b[t];
    w2[t] = att2w[t];
  }
  __syncthreads();
  int n = nc*128 + (t >> 1);
  int half = (t & 1) * 64;
  const float* xr = xa + ((size_t)b*1024 + n)*128 + half;
  float acc = 0.0f;
#pragma unroll
  for (int i = 0; i < 16; i++) {
    int kk = i*4;
    float4 v = *(const float4*)(xr + kk);
    int kg = half + kk;
    acc += fmaxf(v.x + rb[kg+0], 0.0f)*w2[kg+0]
         + fmaxf(v.y + rb[kg+1], 0.0f)*w2[kg+1]
         + fmaxf(v.z + rb[kg+2], 0.0f)*w2[kg+2]
         + fmaxf(v.w + rb[kg+3], 0.0f)*w2[kg+3];
  }
  acc += __shfl_xor(acc, 1, 64);
  if ((t & 1) == 0) lg[(size_t)b*1024 + n] = acc + att2b[0];
}

// ---------------- pooled bf16-emb partials with in-block softmax; lg==nullptr -> uniform ----------------
// 128 blocks = b(32) x nch(4)
__global__ __launch_bounds__(256) void k_poolemb(const unsigned* __restrict__ embh,
        const float* __restrict__ lg, float* __restrict__ pp) {
  int wb = blockIdx.x;
  int b = wb >> 2, nch = wb & 3;
  int tid = threadIdx.x;
  __shared__ float ws[256];
  __shared__ float red[256];
  if (lg) {
    float mx = -1e30f;
#pragma unroll
    for (int i = 0; i < 4; i++) mx = fmaxf(mx, lg[b*1024 + tid + i*256]);
    red[tid] = mx; __syncthreads();
    for (int s = 128; s > 0; s >>= 1) { if (tid < s) red[tid] = fmaxf(red[tid], red[tid+s]); __syncthreads(); }
    float m = red[0]; __syncthreads();
    float sum = 0.0f;
#pragma unroll
    for (int i = 0; i < 4; i++) sum += expf(lg[b*1024 + tid + i*256] - m);
    red[tid] = sum; __syncthreads();
    for (int s = 128; s > 0; s >>= 1) { if (tid < s) red[tid] += red[tid+s]; __syncthreads(); }
    float inv = 1.0f / red[0];
    __syncthreads();
    ws[tid] = expf(lg[b*1024 + nch*256 + tid] - m) * inv;
  } else {
    ws[tid] = 1.0f;
  }
  __syncthreads();
  int pu = tid & 127, ng = tid >> 7;
  const unsigned* eb = embh + (size_t)(b*1024 + nch*256 + ng*128)*128 + pu;
  float a0 = 0.0f, a1 = 0.0f;
#pragma unroll 4
  for (int n = 0; n < 128; n++) {
    unsigned u = eb[(size_t)n*128];
    float w = ws[ng*128 + n];
    a0 += w * bflo(u);
    a1 += w * bfhi(u);
  }
  int p = nch*2 + ng;
  pp[((size_t)p*32 + b)*256 + pu*2]     = a0;
  pp[((size_t)p*32 + b)*256 + pu*2 + 1] = a1;
}

// ---------------- fused: pe = scale * sum_p pp ; P[b][o] = pe[b].up_w[o] + up_b[o] ----------------
__global__ __launch_bounds__(256) void k_pool_pgemm(const float* __restrict__ pp,
        const float* __restrict__ up_w, const float* __restrict__ up_b,
        float* __restrict__ Pout, float scale) {
  int wb = blockIdx.x;             // 128 = b(32) x oc(4)
  int b = wb >> 2, oc = wb & 3;
  int tid = threadIdx.x;
  __shared__ float pe[256];
  float s = 0.0f;
#pragma unroll
  for (int p = 0; p < 8; p++) s += pp[((size_t)p*32 + b)*256 + tid];
  pe[tid] = s * scale;
  __syncthreads();
  int o = oc*256 + tid;
  const float* wr = up_w + (size_t)o*256;
  float acc = up_b[o];
#pragma unroll 8
  for (int d = 0; d < 256; d += 4) {
    float4 w4 = *(const float4*)(wr + d);
    acc += w4.x*pe[d] + w4.y*pe[d+1] + w4.z*pe[d+2] + w4.w*pe[d+3];
  }
  Pout[(size_t)b*1024 + o] = acc;
}

// ---------------- final energy ----------------
__global__ void k_out(const float* __restrict__ c, const float* __restrict__ ew,
                      const float* __restrict__ eb, float* __restrict__ out) {
  int b = blockIdx.x, t = threadIdx.x;   // 32 x 64
  float acc = 0.0f;
  for (int d = t; d < 1024; d += 64) acc += c[b*1024 + d] * ew[d];
  for (int off = 32; off > 0; off >>= 1) acc += __shfl_down(acc, off, 64);
  if (t == 0) out[b] = acc + eb[0];
}

extern "C" void kernel_launch(void* const* d_in, const int* in_sizes, int n_in,
                              void* d_out, int out_size, void* d_ws, size_t ws_size,
                              hipStream_t stream) {
  const int*   x_int  = (const int*)d_in[0];
  const float* x_xyz  = (const float*)d_in[1];
  const float* am     = (const float*)d_in[2];
  const float* el     = (const float*)d_in[3];
  const float* po     = (const float*)d_in[4];
  const float* xyz_w  = (const float*)d_in[5];
  const float* xyz_b  = (const float*)d_in[6];
  const float* up_w   = (const float*)d_in[7];
  const float* up_b   = (const float*)d_in[8];
  const float* w_ih   = (const float*)d_in[9];
  const float* w_hh   = (const float*)d_in[10];
  const float* b_ih   = (const float*)d_in[11];
  const float* b_hh   = (const float*)d_in[12];
  const float* att1_w = (const float*)d_in[13];
  const float* att1_b = (const float*)d_in[14];
  const float* att2_w = (const float*)d_in[15];
  const float* att2_b = (const float*)d_in[16];
  const float* en_w   = (const float*)d_in[17];
  const float* en_b   = (const float*)d_in[18];
  float* out = (float*)d_out;

  char* ws = (char*)d_ws;
  size_t off = 0;
  auto alloc = [&](size_t bytes) { void* p = ws + off; off += (bytes + 255) & ~(size_t)255; return p; };
  unsigned* embh = (unsigned*)alloc((size_t)BN*128*4);    // 16.8 MB (bf16x2 hi)
  unsigned* embl = (unsigned*)alloc((size_t)BN*128*4);    // 16.8 MB (bf16x2 lo)
  unsigned* wt2  = (unsigned*)alloc((size_t)1536*4096*4); // 25.2 MB
  float*    xa   = (float*)alloc((size_t)BN*128*4);       // 16.8 MB
  float*    wcp  = (float*)alloc((size_t)8*128*256*4);    // 1 MB
  unsigned* wchh = (unsigned*)alloc((size_t)128*128*4);
  unsigned* wchl = (unsigned*)alloc((size_t)128*128*4);
  float*    bc   = (float*)alloc((size_t)128*4);
  float*    gp   = (float*)alloc((size_t)KS*32*4096*4);   // 12.6 MB
  float*    pp   = (float*)alloc((size_t)8*32*256*4);     // 256 KB
  float*    P    = (float*)alloc((size_t)32*1024*4);
  float*    h    = (float*)alloc((size_t)32*1024*4);
  float*    c    = (float*)alloc((size_t)32*1024*4);
  float*    rap  = (float*)alloc((size_t)4*32*128*4);
  float*    lg   = (float*)alloc((size_t)32*1024*4);
  (void)ws_size; (void)in_sizes; (void)n_in; (void)out_size;

  k_zero<<<128, 256, 0, stream>>>(c);
  k_emb<<<BN, 256, 0, stream>>>(x_int, x_xyz, am, el, po, xyz_w, xyz_b, embh, embl);
  k_wt<<<dim3(128, 96), 256, 0, stream>>>(w_ih, w_hh, wt2);
  k_wc1<<<dim3(128, 8), 256, 0, stream>>>(up_w, att1_w, wcp);
  k_wc2<<<128, 256, 0, stream>>>(wcp, wchh, wchl);
  k_bc<<<128, 64, 0, stream>>>(up_b, att1_w, bc);
  // xa = emb @ wc^T + bc via MFMA (M=32768, K=256, N=128), 3-term hi/lo split
  k_gemm_mfma<<<BN/32, 256, 0, stream>>>(embh, embl, wchh, wchl, bc, xa);
  // P0 = mean path (uniform weights, scale 1/1024 in pgemm)
  k_poolemb<<<128, 256, 0, stream>>>(embh, nullptr, pp);
  k_pool_pgemm<<<128, 256, 0, stream>>>(pp, up_w, up_b, P, 1.0f/1024.0f);

  for (int step = 0; step < 6; step++) {
    int nks = (step == 0) ? 8 : KS;   // h==0 on step 0 -> ks>=8 partials are exactly zero
    k_gates<<<dim3(32, nks), 256, 0, stream>>>(P, h, wt2, gp);
    k_lstm_rap<<<128, 256, 0, stream>>>(gp, b_ih, b_hh, c, h, att1_w, rap,
                                        step < 5 ? 1 : 0, nks);
    if (step < 5) {  // last step's attention output is unused
      k_logits<<<dim3(32, 8), 256, 0, stream>>>(xa, rap, att1_b, att2_w, att2_b, lg);
      k_poolemb<<<128, 256, 0, stream>>>(embh, lg, pp);
      k_pool_pgemm<<<128, 256, 0, stream>>>(pp, up_w, up_b, P, 1.0f);
    }
  }
  k_out<<<32, 64, 0, stream>>>(c, en_w, en_b, out);
}